// Round 1
// baseline (11.543 us; speedup 1.0000x reference)
//
#include <hip/hip_runtime.h>

#define CL_BATCH 256
#define CL_FEAT  512
#define CL_CLAMP_MIN 1e-12f
#define CL_CLAMP_MAX 1e12f

// Kernel 1: one 64-lane wave per batch row.
// Each lane loads 2x float4 (8 floats) of x-row and gathered center-row,
// accumulates squared diff, wave-reduces, lane 0 clamps + writes ws[b].
__global__ __launch_bounds__(64) void center_loss_rows(
    const float* __restrict__ x,
    const int* __restrict__ label,
    const float* __restrict__ centers,
    float* __restrict__ row_dist)
{
    const int b = blockIdx.x;     // 0..255
    const int t = threadIdx.x;    // 0..63

    const int lbl = label[b];

    const float4* __restrict__ xr =
        reinterpret_cast<const float4*>(x + (size_t)b * CL_FEAT);
    const float4* __restrict__ cr =
        reinterpret_cast<const float4*>(centers + (size_t)lbl * CL_FEAT);

    // 512 floats per row = 128 float4 = 64 lanes x 2
    float4 xv0 = xr[t];
    float4 cv0 = cr[t];
    float4 xv1 = xr[t + 64];
    float4 cv1 = cr[t + 64];

    float s = 0.0f;
    float d;
    d = xv0.x - cv0.x; s = fmaf(d, d, s);
    d = xv0.y - cv0.y; s = fmaf(d, d, s);
    d = xv0.z - cv0.z; s = fmaf(d, d, s);
    d = xv0.w - cv0.w; s = fmaf(d, d, s);
    d = xv1.x - cv1.x; s = fmaf(d, d, s);
    d = xv1.y - cv1.y; s = fmaf(d, d, s);
    d = xv1.z - cv1.z; s = fmaf(d, d, s);
    d = xv1.w - cv1.w; s = fmaf(d, d, s);

    // 64-lane butterfly reduce
    #pragma unroll
    for (int off = 32; off > 0; off >>= 1)
        s += __shfl_down(s, off, 64);

    if (t == 0) {
        s = fminf(fmaxf(s, CL_CLAMP_MIN), CL_CLAMP_MAX);
        row_dist[b] = s;
    }
}

// Kernel 2: one wave deterministically reduces the 256 per-row distances.
__global__ __launch_bounds__(64) void center_loss_reduce(
    const float* __restrict__ row_dist,
    float* __restrict__ out)
{
    const int t = threadIdx.x;  // 0..63
    const float4* __restrict__ r = reinterpret_cast<const float4*>(row_dist);
    float4 v = r[t];            // 64 lanes x 4 = 256 values
    float s = (v.x + v.y) + (v.z + v.w);

    #pragma unroll
    for (int off = 32; off > 0; off >>= 1)
        s += __shfl_down(s, off, 64);

    if (t == 0)
        out[0] = s * (1.0f / (float)CL_BATCH);
}

extern "C" void kernel_launch(void* const* d_in, const int* in_sizes, int n_in,
                              void* d_out, int out_size, void* d_ws, size_t ws_size,
                              hipStream_t stream)
{
    const float* x       = (const float*)d_in[0];   // [256, 512] f32
    const int*   label   = (const int*)d_in[1];     // [256] int
    const float* centers = (const float*)d_in[2];   // [100000, 512] f32
    float* out = (float*)d_out;                     // scalar f32
    float* row_dist = (float*)d_ws;                 // 256 floats scratch

    center_loss_rows<<<CL_BATCH, 64, 0, stream>>>(x, label, centers, row_dist);
    center_loss_reduce<<<1, 64, 0, stream>>>(row_dist, out);
}